// Round 10
// baseline (745.187 us; speedup 1.0000x reference)
//
#include <hip/hip_runtime.h>
#include <hip/hip_bf16.h>

#define DEVI __device__ __forceinline__

typedef __bf16 bf16x8 __attribute__((ext_vector_type(8)));
typedef float  f32x4  __attribute__((ext_vector_type(4)));
typedef unsigned short ushort_t;

static constexpr int H = 384, W = 384, BATCH = 2, HW = H * W;
static constexpr int NMSD = 4, BORD = 4, TOPK = 500;
static constexpr float THRESH = 0.8f;
static constexpr int CAP = 2048;    // candidate capacity per image
static constexpr int SORTN = 2048;  // bitonic sort size (>= CAP)

DEVI ushort_t f2b(float f) {
  __hip_bfloat16 h = __float2bfloat16(f);
  ushort_t s;
  __builtin_memcpy(&s, &h, 2);
  return s;
}
DEVI float b2f(ushort_t u) { return __uint_as_float(((unsigned)u) << 16); }

DEVI void gload_lds16(const void* g, void* l) {
  __builtin_amdgcn_global_load_lds((const __attribute__((address_space(1))) void*)g,
                                   (__attribute__((address_space(3))) void*)l,
                                   16, 0, 0);
}

// ---------------------------------------------------------------- unified setup
// conv weights: OIHW fp32 [O][I][3][3] -> bf16 [9][O][I]  (round-4 validated layout)
DEVI void repack9(const float* __restrict__ src, ushort_t* __restrict__ dst,
                  int d, int O, int I) {
  int t = d / (O * I);
  int r = d % (O * I);
  int o = r / I, i = r % I;
  dst[d] = f2b(src[(o * I + i) * 9 + t]);
}

__global__ __launch_bounds__(256) void setup_all(
    const float* __restrict__ w2s, ushort_t* __restrict__ wp2,
    const float* __restrict__ w3s, ushort_t* __restrict__ wp3,
    const float* __restrict__ w4s, ushort_t* __restrict__ wp4,
    const float* __restrict__ wds, ushort_t* __restrict__ wpd,
    const float* __restrict__ dw1, ushort_t* __restrict__ w1t,
    const float* __restrict__ dw2, float* __restrict__ w2t,
    ushort_t* __restrict__ zer, int* __restrict__ cnt) {
  int d = blockIdx.x * 256 + threadIdx.x;
  if (d < 1024) { zer[d] = 0; if (d < 2) cnt[d] = 0; return; }
  d -= 1024;
  if (d < 36864)  { repack9(w2s, wp2, d, 64, 64);   return; }
  d -= 36864;
  if (d < 73728)  { repack9(w3s, wp3, d, 128, 64);  return; }
  d -= 73728;
  if (d < 147456) { repack9(w4s, wp4, d, 128, 128); return; }
  d -= 147456;
  if (d < 147456) { repack9(wds, wpd, d, 128, 128); return; }
  d -= 147456;
  if (d < 294912) {  // des_w1 [256][1152] -> bf16 [288][256][4], k reordered t-major
    int o = d / 1152, k = d % 1152;      // k = ci*9 + t (OIHW flat)
    int kp = (k % 9) * 128 + (k / 9);    // k' = t*128 + ci  (coalesced gather order)
    w1t[(size_t)(kp >> 2) * 1024 + o * 4 + (kp & 3)] = f2b(dw1[d]);
    return;
  }
  d -= 294912;
  if (d < 32768) {   // des_w2 [128][256] -> fp32 [256][128]
    int o = d / 128, c = d % 128;
    w2t[d] = dw2[c * 256 + o];
  }
}
// total elements = 1024+36864+73728+147456+147456+294912+32768 = 734208 = 2868*256

// ---------------------------------------------------------------- conv1 (1->64) fp32 direct, bf16 NHWC out
__global__ __launch_bounds__(256) void conv1_kernel(
    const float* __restrict__ img, const float* __restrict__ w,
    const float* __restrict__ bias, ushort_t* __restrict__ xout) {
  __shared__ __align__(16) float wt[9 * 64];
  __shared__ float bs[64];
  const int tid = threadIdx.x;
  for (int j = tid; j < 576; j += 256) {
    int co = j / 9, t = j % 9;
    wt[t * 64 + co] = w[j];
  }
  if (tid < 64) bs[tid] = bias[tid];
  __syncthreads();

  const int p = blockIdx.x * 256 + tid;
  const int b = p / HW, rem = p % HW;
  const int y = rem / W, x = rem % W;

  float in[9];
#pragma unroll
  for (int t = 0; t < 9; ++t) {
    int yy = y + t / 3 - 1, xx = x + t % 3 - 1;
    in[t] = (yy >= 0 && yy < H && xx >= 0 && xx < W) ? img[(size_t)b * HW + yy * W + xx] : 0.f;
  }
  float acc[64];
#pragma unroll
  for (int c = 0; c < 64; ++c) acc[c] = bs[c];
#pragma unroll
  for (int t = 0; t < 9; ++t) {
    float v = in[t];
#pragma unroll
    for (int c4 = 0; c4 < 16; ++c4) {
      float4 w4 = *reinterpret_cast<const float4*>(&wt[t * 64 + c4 * 4]);
      acc[c4 * 4 + 0] += w4.x * v;
      acc[c4 * 4 + 1] += w4.y * v;
      acc[c4 * 4 + 2] += w4.z * v;
      acc[c4 * 4 + 3] += w4.w * v;
    }
  }
  ushort_t* op = xout + (size_t)p * 64;
#pragma unroll
  for (int g = 0; g < 8; ++g) {
    uint4 u;
    u.x = (unsigned)f2b(fmaxf(acc[g * 8 + 0], 0.f)) | ((unsigned)f2b(fmaxf(acc[g * 8 + 1], 0.f)) << 16);
    u.y = (unsigned)f2b(fmaxf(acc[g * 8 + 2], 0.f)) | ((unsigned)f2b(fmaxf(acc[g * 8 + 3], 0.f)) << 16);
    u.z = (unsigned)f2b(fmaxf(acc[g * 8 + 4], 0.f)) | ((unsigned)f2b(fmaxf(acc[g * 8 + 5], 0.f)) << 16);
    u.w = (unsigned)f2b(fmaxf(acc[g * 8 + 6], 0.f)) | ((unsigned)f2b(fmaxf(acc[g * 8 + 7], 0.f)) << 16);
    *reinterpret_cast<uint4*>(op + g * 8) = u;
  }
}

// ---------------------------------------------------------------- 3x3 conv, bf16 MFMA implicit GEMM (v4)
// Round-4 single-buffer 2-barrier sync (validated; cross-block TLP hides the
// drain at 3-4 blocks/CU). Geometry enlarged to cut LDS bytes/FLOP:
// wave tile MFRAG*16 co x NFRAG*16 px; block tile COUT x NT px of one row.
// Phase = (dy, 32ci chunk).
template <int CIN, int COUT, int MFRAG, int NFRAG, int NT>
__global__ __launch_bounds__(256, 3) void conv3x3_mfma(
    const ushort_t* __restrict__ xin, const ushort_t* __restrict__ wp,
    const float* __restrict__ bias, ushort_t* __restrict__ xout,
    const ushort_t* __restrict__ zer) {
  constexpr int CC = CIN / 32;          // ci chunks
  constexpr int ACH3 = 3 * COUT / 16;   // A chunks per phase (3 taps)
  constexpr int APW = ACH3 / 4;         // A chunks per wave
  constexpr int BCH = (NT + 2 + 15) / 16;  // staged B chunks (NT+2 halo rows)

  __shared__ __align__(16) ushort_t lA[3 * COUT * 32];  // [tt][co][32ci]
  __shared__ __align__(16) ushort_t lB[BCH * 16 * 32];  // [px-(x0-1)][32ci]

  const int x0 = (blockIdx.x % (W / NT)) * NT;
  const int y = blockIdx.x / (W / NT);
  const int b = blockIdx.y;

  const int tid = threadIdx.x;
  const int wid = tid >> 6, lane = tid & 63;
  const int wr = wid >> 1, wc = wid & 1;
  const int l4 = lane >> 2;        // staging row within 16-row chunk
  const int lb8 = (lane & 3) * 8;  // staging bf16 offset within 64B row
  const int kg = lane >> 4;        // k-group 0..3
  const int lr = lane & 15;

  const f32x4 fz = {0.f, 0.f, 0.f, 0.f};
  f32x4 acc[MFRAG][NFRAG];
#pragma unroll
  for (int m = 0; m < MFRAG; ++m)
#pragma unroll
    for (int n = 0; n < NFRAG; ++n) acc[m][n] = fz;

#pragma unroll 1
  for (int dy = -1; dy <= 1; ++dy) {
    const int yy = y + dy;
    const bool rowok = (yy >= 0) && (yy < H);
    const ushort_t* srow = xin + ((size_t)(b * H + yy) * W) * CIN;
#pragma unroll 1
    for (int cc = 0; cc < CIN; cc += 32) {
      // stage A: 3 taps x COUT rows x 64B (tap t = (dy+1)*3 + tt)
#pragma unroll
      for (int j = 0; j < APW; ++j) {
        int ch = wid * APW + j;
        int row = ch * 16 + l4;            // 0 .. 3*COUT-1 (tt-major)
        int tt = row / COUT, co = row % COUT;
        const ushort_t* src =
            wp + ((size_t)((dy + 1) * 3 + tt) * COUT + co) * CIN + cc + lb8;
        gload_lds16(src, &lA[ch * 512]);
      }
      // stage B: px = x0-1+row, valid rows < NT+2
      for (int ch = wid; ch < BCH; ch += 4) {
        int row = ch * 16 + l4;
        int xx = x0 - 1 + row;
        const ushort_t* src = (rowok && row < NT + 2 && xx >= 0 && xx < W)
                                  ? srow + (size_t)xx * CIN + cc + lb8
                                  : zer + lb8;
        gload_lds16(src, &lB[ch * 512]);
      }
      __syncthreads();
#pragma unroll
      for (int tt = 0; tt < 3; ++tt) {  // dx = tt-1; lB row = local_px + tt
        bf16x8 af[MFRAG], bfr[NFRAG];
#pragma unroll
        for (int m = 0; m < MFRAG; ++m)
          af[m] = *reinterpret_cast<const bf16x8*>(
              &lA[(tt * COUT + wr * MFRAG * 16 + m * 16 + lr) * 32 + kg * 8]);
#pragma unroll
        for (int n = 0; n < NFRAG; ++n)
          bfr[n] = *reinterpret_cast<const bf16x8*>(
              &lB[(wc * NFRAG * 16 + n * 16 + lr + tt) * 32 + kg * 8]);
#pragma unroll
        for (int m = 0; m < MFRAG; ++m)
#pragma unroll
          for (int n = 0; n < NFRAG; ++n)
            acc[m][n] = __builtin_amdgcn_mfma_f32_16x16x32_bf16(af[m], bfr[n], acc[m][n], 0, 0, 0);
      }
      __syncthreads();
    }
  }

  // epilogue: C/D layout col(=px)=lane&15, row(=co)=(lane>>4)*4+reg  [m89]
  const int lq = lane >> 4;
  ushort_t* orow = xout + ((size_t)(b * H + y) * W) * COUT;
#pragma unroll
  for (int m = 0; m < MFRAG; ++m) {
    const int co = wr * MFRAG * 16 + m * 16 + lq * 4;
    const float4 bv = *reinterpret_cast<const float4*>(&bias[co]);
#pragma unroll
    for (int n = 0; n < NFRAG; ++n) {
      const int px = x0 + wc * NFRAG * 16 + n * 16 + lr;
      f32x4 v = acc[m][n];
      ushort4 pk;
      pk.x = f2b(fmaxf(v[0] + bv.x, 0.f));
      pk.y = f2b(fmaxf(v[1] + bv.y, 0.f));
      pk.z = f2b(fmaxf(v[2] + bv.z, 0.f));
      pk.w = f2b(fmaxf(v[3] + bv.w, 0.f));
      *reinterpret_cast<ushort4*>(&orow[(size_t)px * COUT + co]) = pk;
    }
  }
}

// ---------------------------------------------------------------- det2 (1x1,128->1) + sigmoid + row-max fused
__global__ __launch_bounds__(384) void det2_rowmax(
    const ushort_t* __restrict__ dbuf, const float* __restrict__ w2,
    const float* __restrict__ b2, float* __restrict__ prob,
    float* __restrict__ tmp) {
  __shared__ float ws[128];
  __shared__ float pr[W];
  const int tid = threadIdx.x;
  if (tid < 128) ws[tid] = w2[tid];
  __syncthreads();
  const int p = blockIdx.x * W + tid;  // blockIdx.x = b*H + y
  const ushort_t* dp = dbuf + (size_t)p * 128;
  float acc = b2[0];
#pragma unroll
  for (int k = 0; k < 128; k += 8) {
    uint4 q = *reinterpret_cast<const uint4*>(dp + k);
    acc += __uint_as_float(q.x << 16) * ws[k + 0];
    acc += __uint_as_float(q.x & 0xffff0000u) * ws[k + 1];
    acc += __uint_as_float(q.y << 16) * ws[k + 2];
    acc += __uint_as_float(q.y & 0xffff0000u) * ws[k + 3];
    acc += __uint_as_float(q.z << 16) * ws[k + 4];
    acc += __uint_as_float(q.z & 0xffff0000u) * ws[k + 5];
    acc += __uint_as_float(q.w << 16) * ws[k + 6];
    acc += __uint_as_float(q.w & 0xffff0000u) * ws[k + 7];
  }
  float pv = 1.f / (1.f + expf(-acc));
  prob[p] = pv;
  pr[tid] = pv;
  __syncthreads();
  float m = -1e30f;
#pragma unroll
  for (int d = -NMSD; d <= NMSD; ++d) {
    int xx = tid + d;
    if (xx >= 0 && xx < W) m = fmaxf(m, pr[xx]);
  }
  tmp[p] = m;
}

// ---------------------------------------------------------------- col-max + candidate collection
__global__ __launch_bounds__(256) void colmax9_cand(
    const float* __restrict__ tmp, const float* __restrict__ prob,
    int* __restrict__ cnt, float* __restrict__ candv, int* __restrict__ candi) {
  const int p = blockIdx.x * 256 + threadIdx.x;
  const int b = p / HW, rem = p % HW;
  const int y = rem / W, x = rem % W;
  float m = -1e30f;
#pragma unroll
  for (int d = -NMSD; d <= NMSD; ++d) {
    int yy = y + d;
    if (yy >= 0 && yy < H) m = fmaxf(m, tmp[(size_t)b * HW + yy * W + x]);
  }
  float pv = prob[p];
  bool keep = (pv >= m) && (pv > THRESH) &&
              (y >= BORD) && (y < H - BORD) && (x >= BORD) && (x < W - BORD);
  if (keep) {
    int pos = atomicAdd(&cnt[b], 1);
    if (pos < CAP) {
      candv[b * CAP + pos] = pv;
      candi[b * CAP + pos] = rem;
    }
  }
}

// ---------------------------------------------------------------- top-k with JAX tie semantics
__global__ __launch_bounds__(256) void select_topk(
    const int* __restrict__ cnt, const float* __restrict__ candv,
    const int* __restrict__ candi, float* __restrict__ pos_out,
    int* __restrict__ topi_g) {
  __shared__ float sv[SORTN];
  __shared__ int si[SORTN];
  __shared__ int tail[TOPK];
  const int b = blockIdx.x, tid = threadIdx.x;
  int nc = cnt[b];
  if (nc > CAP) nc = CAP;
  for (int j = tid; j < SORTN; j += 256) {
    if (j < nc) {
      sv[j] = candv[b * CAP + j];
      si[j] = candi[b * CAP + j];
    } else {
      sv[j] = -1.f;
      si[j] = 0x7fffffff;
    }
  }
  __syncthreads();
  if (nc > 0) {  // block-uniform: skip sort when candidate set empty
    for (int k = 2; k <= SORTN; k <<= 1) {
      for (int j = k >> 1; j > 0; j >>= 1) {
        for (int i = tid; i < SORTN; i += 256) {
          int l = i ^ j;
          if (l > i) {
            float vi = sv[i], vl = sv[l];
            int ii = si[i], il = si[l];
            bool i_better = (vi > vl) || (vi == vl && ii < il);
            bool desc = ((i & k) == 0);
            bool sw = desc ? (!i_better) : i_better;
            if (sw) {
              sv[i] = vl; sv[l] = vi;
              si[i] = il; si[l] = ii;
            }
          }
        }
        __syncthreads();
      }
    }
  }
  if (tid == 0) {
    int need = TOPK - nc;
    if (need < 0) need = 0;
    int idx = 0, filled = 0;
    while (filled < need && idx < HW) {
      bool used = false;
      for (int q = 0; q < nc; ++q)
        if (si[q] == idx) { used = true; break; }
      if (!used) tail[filled++] = idx;
      ++idx;
    }
  }
  __syncthreads();
  for (int k2 = tid; k2 < TOPK; k2 += 256) {
    float v; int idx;
    if (k2 < nc) { v = sv[k2]; idx = si[k2]; }
    else         { v = 0.f;    idx = tail[k2 - nc]; }
    pos_out[((size_t)b * TOPK + k2) * 3 + 0] = (float)(idx / W);
    pos_out[((size_t)b * TOPK + k2) * 3 + 1] = (float)(idx % W);
    pos_out[((size_t)b * TOPK + k2) * 3 + 2] = v;
    topi_g[b * TOPK + k2] = idx;
  }
}

// ---------------------------------------------------------------- descriptor head at keypoints only
// xf gather is t-major (k' = t*128+ci): consecutive threads read consecutive
// ci at one tap -> coalesced 256B runs. w1t repacked in matching order.
__global__ __launch_bounds__(256) void des_head(
    const ushort_t* __restrict__ feats, const int* __restrict__ topi_g,
    const ushort_t* __restrict__ w1t, const float* __restrict__ b1,
    const float* __restrict__ w2t, const float* __restrict__ b2,
    const float* __restrict__ scale, float* __restrict__ desc_out) {
  __shared__ __align__(16) float xf[1152];  // k' = t*128 + ci
  __shared__ __align__(16) float es[256];
  __shared__ float rs[128];
  __shared__ float nrm_s;
  const int g = blockIdx.x;
  const int b = g / TOPK;
  const int tid = threadIdx.x;
  const int idx = topi_g[g];
  const int y = idx / W, x = idx % W;
  for (int j = tid; j < 1152; j += 256) {
    int t = j >> 7, ci = j & 127;
    int yy = y + t / 3 - 1, xx = x + t % 3 - 1;
    xf[j] = (yy >= 0 && yy < H && xx >= 0 && xx < W)
                ? b2f(feats[((size_t)(b * H + yy) * W + xx) * 128 + ci])
                : 0.f;
  }
  __syncthreads();
  float e = b1[tid];
  const ushort4* w4p = reinterpret_cast<const ushort4*>(w1t);
#pragma unroll 4
  for (int k4 = 0; k4 < 288; ++k4) {
    ushort4 wv = w4p[(size_t)k4 * 256 + tid];
    float4 x4 = *reinterpret_cast<const float4*>(&xf[k4 * 4]);
    e += b2f(wv.x) * x4.x + b2f(wv.y) * x4.y + b2f(wv.z) * x4.z + b2f(wv.w) * x4.w;
  }
  es[tid] = fmaxf(e, 0.f);
  __syncthreads();
  if (tid < 128) {
    float r = b2[tid];
#pragma unroll 4
    for (int o = 0; o < 256; ++o) r += es[o] * w2t[o * 128 + tid];
    rs[tid] = r;
  }
  __syncthreads();
  if (tid < 64) {
    float v = rs[tid] * rs[tid] + rs[tid + 64] * rs[tid + 64];
    for (int off = 32; off > 0; off >>= 1) v += __shfl_down(v, off);
    if (tid == 0) nrm_s = sqrtf(v);
  }
  __syncthreads();
  if (tid < 128) {
    float nrm = fmaxf(nrm_s, 1e-12f);
    desc_out[(size_t)g * 128 + tid] = rs[tid] * (scale[0] / nrm);
  }
}

// ---------------------------------------------------------------- launch
extern "C" void kernel_launch(void* const* d_in, const int* in_sizes, int n_in,
                              void* d_out, int out_size, void* d_ws, size_t ws_size,
                              hipStream_t stream) {
  (void)in_sizes; (void)n_in; (void)out_size; (void)ws_size;
  const float* images = (const float*)d_in[0];
  const float* bbw1 = (const float*)d_in[1];  const float* bbb1 = (const float*)d_in[2];
  const float* bbw2 = (const float*)d_in[3];  const float* bbb2 = (const float*)d_in[4];
  const float* bbw3 = (const float*)d_in[5];  const float* bbb3 = (const float*)d_in[6];
  const float* bbw4 = (const float*)d_in[7];  const float* bbb4 = (const float*)d_in[8];
  const float* dtw1 = (const float*)d_in[9];  const float* dtb1 = (const float*)d_in[10];
  const float* dtw2 = (const float*)d_in[11]; const float* dtb2 = (const float*)d_in[12];
  const float* dsw1 = (const float*)d_in[13]; const float* dsb1 = (const float*)d_in[14];
  const float* dsw2 = (const float*)d_in[15]; const float* dsb2 = (const float*)d_in[16];
  const float* scale = (const float*)d_in[17];

  char* ws = (char*)d_ws;
  constexpr size_t SZ64 = (size_t)BATCH * HW * 64 * 2;   // 37,748,736
  constexpr size_t SZ128 = (size_t)BATCH * HW * 128 * 2; // 75,497,472

  // Two big regions, time-multiplexed by dataflow (~155 MB total):
  //   region A [0, SZ128):        x1 + x2   -->  fts
  //   region B [SZ128, 2*SZ128):  x3        -->  dbuf
  ushort_t* x1   = (ushort_t*)ws;
  ushort_t* x2   = (ushort_t*)(ws + SZ64);
  ushort_t* x3   = (ushort_t*)(ws + SZ128);
  ushort_t* fts  = (ushort_t*)ws;              // alias x1+x2
  ushort_t* dbuf = (ushort_t*)(ws + SZ128);    // alias x3

  size_t off = 2 * SZ128;
  auto alloc = [&](size_t bytes) {
    char* p = ws + off;
    off = (off + bytes + 255) & ~(size_t)255;
    return p;
  };
  float* prob = (float*)alloc((size_t)BATCH * HW * 4);
  float* tmp  = (float*)alloc((size_t)BATCH * HW * 4);
  ushort_t* wp2 = (ushort_t*)alloc(9 * 64 * 64 * 2);
  ushort_t* wp3 = (ushort_t*)alloc(9 * 128 * 64 * 2);
  ushort_t* wp4 = (ushort_t*)alloc(9 * 128 * 128 * 2);
  ushort_t* wpd = (ushort_t*)alloc(9 * 128 * 128 * 2);
  ushort_t* w1t = (ushort_t*)alloc(288 * 256 * 4 * 2);
  float*    w2t = (float*)alloc(256 * 128 * 4);
  ushort_t* zer = (ushort_t*)alloc(2048);
  int* cnt      = (int*)alloc(256);
  float* candv  = (float*)alloc((size_t)BATCH * CAP * 4);
  int* candi    = (int*)alloc((size_t)BATCH * CAP * 4);
  int* topi_g   = (int*)alloc((size_t)BATCH * TOPK * 4);

  float* desc_out = (float*)d_out;
  float* pos_out  = (float*)d_out + (size_t)BATCH * TOPK * 128;

  setup_all<<<2868, 256, 0, stream>>>(bbw2, wp2, bbw3, wp3, bbw4, wp4, dtw1, wpd,
                                      dsw1, w1t, dsw2, w2t, zer, cnt);

  conv1_kernel<<<BATCH * HW / 256, 256, 0, stream>>>(images, bbw1, bbb1, x1);
  conv3x3_mfma<64, 64, 2, 4, 128>  <<<dim3(3 * H, BATCH), 256, 0, stream>>>(x1, wp2, bbb2, x2, zer);
  conv3x3_mfma<64, 128, 4, 6, 192> <<<dim3(2 * H, BATCH), 256, 0, stream>>>(x2, wp3, bbb3, x3, zer);
  conv3x3_mfma<128, 128, 4, 6, 192><<<dim3(2 * H, BATCH), 256, 0, stream>>>(x3, wp4, bbb4, fts, zer);
  conv3x3_mfma<128, 128, 4, 6, 192><<<dim3(2 * H, BATCH), 256, 0, stream>>>(fts, wpd, dtb1, dbuf, zer);

  det2_rowmax<<<BATCH * H, 384, 0, stream>>>(dbuf, dtw2, dtb2, prob, tmp);
  colmax9_cand<<<BATCH * HW / 256, 256, 0, stream>>>(tmp, prob, cnt, candv, candi);
  select_topk<<<BATCH, 256, 0, stream>>>(cnt, candv, candi, pos_out, topi_g);
  des_head<<<BATCH * TOPK, 256, 0, stream>>>(fts, topi_g, w1t, dsb1, w2t, dsb2, scale, desc_out);
}

// Round 12
// 504.595 us; speedup vs baseline: 1.4768x; 1.4768x over previous
//
#include <hip/hip_runtime.h>
#include <hip/hip_bf16.h>

#define DEVI __device__ __forceinline__

typedef __bf16 bf16x8 __attribute__((ext_vector_type(8)));
typedef float  f32x4  __attribute__((ext_vector_type(4)));
typedef unsigned short ushort_t;

static constexpr int H = 384, W = 384, BATCH = 2, HW = H * W;
static constexpr int NMSD = 4, BORD = 4, TOPK = 500;
static constexpr float THRESH = 0.8f;
static constexpr int CAP = 2048;    // candidate capacity per image
static constexpr int SORTN = 2048;  // bitonic sort size (>= CAP)

DEVI ushort_t f2b(float f) {
  __hip_bfloat16 h = __float2bfloat16(f);
  ushort_t s;
  __builtin_memcpy(&s, &h, 2);
  return s;
}
DEVI float b2f(ushort_t u) { return __uint_as_float(((unsigned)u) << 16); }

DEVI void gload_lds16(const void* g, void* l) {
  __builtin_amdgcn_global_load_lds((const __attribute__((address_space(1))) void*)g,
                                   (__attribute__((address_space(3))) void*)l,
                                   16, 0, 0);
}

// ---------------------------------------------------------------- unified setup
// conv weights: OIHW fp32 [O][I][3][3] -> bf16 [9][O][I]  (round-4 validated layout)
DEVI void repack9(const float* __restrict__ src, ushort_t* __restrict__ dst,
                  int d, int O, int I) {
  int t = d / (O * I);
  int r = d % (O * I);
  int o = r / I, i = r % I;
  dst[d] = f2b(src[(o * I + i) * 9 + t]);
}

__global__ __launch_bounds__(256) void setup_all(
    const float* __restrict__ w2s, ushort_t* __restrict__ wp2,
    const float* __restrict__ w3s, ushort_t* __restrict__ wp3,
    const float* __restrict__ w4s, ushort_t* __restrict__ wp4,
    const float* __restrict__ wds, ushort_t* __restrict__ wpd,
    const float* __restrict__ dw1, ushort_t* __restrict__ w1t,
    const float* __restrict__ dw2, float* __restrict__ w2t,
    ushort_t* __restrict__ zer, int* __restrict__ cnt) {
  int d = blockIdx.x * 256 + threadIdx.x;
  if (d < 1024) { zer[d] = 0; if (d < 2) cnt[d] = 0; return; }
  d -= 1024;
  if (d < 36864)  { repack9(w2s, wp2, d, 64, 64);   return; }
  d -= 36864;
  if (d < 73728)  { repack9(w3s, wp3, d, 128, 64);  return; }
  d -= 73728;
  if (d < 147456) { repack9(w4s, wp4, d, 128, 128); return; }
  d -= 147456;
  if (d < 147456) { repack9(wds, wpd, d, 128, 128); return; }
  d -= 147456;
  if (d < 294912) {  // des_w1 [256][1152] -> bf16 [288][256][4], k reordered t-major
    int o = d / 1152, k = d % 1152;      // k = ci*9 + t (OIHW flat)
    int kp = (k % 9) * 128 + (k / 9);    // k' = t*128 + ci  (coalesced gather order)
    w1t[(size_t)(kp >> 2) * 1024 + o * 4 + (kp & 3)] = f2b(dw1[d]);
    return;
  }
  d -= 294912;
  if (d < 32768) {   // des_w2 [128][256] -> fp32 [256][128]
    int o = d / 128, c = d % 128;
    w2t[d] = dw2[c * 256 + o];
  }
}
// total elements = 1024+36864+73728+147456+147456+294912+32768 = 734208 = 2868*256

// ---------------------------------------------------------------- conv1 (1->64) fp32 direct, bf16 NHWC out
__global__ __launch_bounds__(256) void conv1_kernel(
    const float* __restrict__ img, const float* __restrict__ w,
    const float* __restrict__ bias, ushort_t* __restrict__ xout) {
  __shared__ __align__(16) float wt[9 * 64];
  __shared__ float bs[64];
  const int tid = threadIdx.x;
  for (int j = tid; j < 576; j += 256) {
    int co = j / 9, t = j % 9;
    wt[t * 64 + co] = w[j];
  }
  if (tid < 64) bs[tid] = bias[tid];
  __syncthreads();

  const int p = blockIdx.x * 256 + tid;
  const int b = p / HW, rem = p % HW;
  const int y = rem / W, x = rem % W;

  float in[9];
#pragma unroll
  for (int t = 0; t < 9; ++t) {
    int yy = y + t / 3 - 1, xx = x + t % 3 - 1;
    in[t] = (yy >= 0 && yy < H && xx >= 0 && xx < W) ? img[(size_t)b * HW + yy * W + xx] : 0.f;
  }
  float acc[64];
#pragma unroll
  for (int c = 0; c < 64; ++c) acc[c] = bs[c];
#pragma unroll
  for (int t = 0; t < 9; ++t) {
    float v = in[t];
#pragma unroll
    for (int c4 = 0; c4 < 16; ++c4) {
      float4 w4 = *reinterpret_cast<const float4*>(&wt[t * 64 + c4 * 4]);
      acc[c4 * 4 + 0] += w4.x * v;
      acc[c4 * 4 + 1] += w4.y * v;
      acc[c4 * 4 + 2] += w4.z * v;
      acc[c4 * 4 + 3] += w4.w * v;
    }
  }
  ushort_t* op = xout + (size_t)p * 64;
#pragma unroll
  for (int g = 0; g < 8; ++g) {
    uint4 u;
    u.x = (unsigned)f2b(fmaxf(acc[g * 8 + 0], 0.f)) | ((unsigned)f2b(fmaxf(acc[g * 8 + 1], 0.f)) << 16);
    u.y = (unsigned)f2b(fmaxf(acc[g * 8 + 2], 0.f)) | ((unsigned)f2b(fmaxf(acc[g * 8 + 3], 0.f)) << 16);
    u.z = (unsigned)f2b(fmaxf(acc[g * 8 + 4], 0.f)) | ((unsigned)f2b(fmaxf(acc[g * 8 + 5], 0.f)) << 16);
    u.w = (unsigned)f2b(fmaxf(acc[g * 8 + 6], 0.f)) | ((unsigned)f2b(fmaxf(acc[g * 8 + 7], 0.f)) << 16);
    *reinterpret_cast<uint4*>(op + g * 8) = u;
  }
}

// ---------------------------------------------------------------- 3x3 conv, bf16 MFMA implicit GEMM (v4b)
// Round-4 single-buffer 2-barrier sync (validated). Geometry enlarged to cut
// LDS bytes/FLOP (NFRAG=6, NT=192). NO min-waves launch bound: round-10's
// (256,3) capped VGPR at 84 < acc footprint (96) -> full acc spill ->
// +550 MB HBM scratch traffic, 193 us. Natural allocation (~150-180 VGPR)
// gives 3 waves/SIMD without spilling.
template <int CIN, int COUT, int MFRAG, int NFRAG, int NT>
__global__ __launch_bounds__(256) void conv3x3_mfma(
    const ushort_t* __restrict__ xin, const ushort_t* __restrict__ wp,
    const float* __restrict__ bias, ushort_t* __restrict__ xout,
    const ushort_t* __restrict__ zer) {
  constexpr int ACH3 = 3 * COUT / 16;   // A chunks per phase (3 taps)
  constexpr int APW = ACH3 / 4;         // A chunks per wave
  constexpr int BCH = (NT + 2 + 15) / 16;  // staged B chunks (NT+2 halo rows)

  __shared__ __align__(16) ushort_t lA[3 * COUT * 32];  // [tt][co][32ci]
  __shared__ __align__(16) ushort_t lB[BCH * 16 * 32];  // [px-(x0-1)][32ci]

  const int x0 = (blockIdx.x % (W / NT)) * NT;
  const int y = blockIdx.x / (W / NT);
  const int b = blockIdx.y;

  const int tid = threadIdx.x;
  const int wid = tid >> 6, lane = tid & 63;
  const int wr = wid >> 1, wc = wid & 1;
  const int l4 = lane >> 2;        // staging row within 16-row chunk
  const int lb8 = (lane & 3) * 8;  // staging bf16 offset within 64B row
  const int kg = lane >> 4;        // k-group 0..3
  const int lr = lane & 15;

  const f32x4 fz = {0.f, 0.f, 0.f, 0.f};
  f32x4 acc[MFRAG][NFRAG];
#pragma unroll
  for (int m = 0; m < MFRAG; ++m)
#pragma unroll
    for (int n = 0; n < NFRAG; ++n) acc[m][n] = fz;

#pragma unroll 1
  for (int dy = -1; dy <= 1; ++dy) {
    const int yy = y + dy;
    const bool rowok = (yy >= 0) && (yy < H);
    const ushort_t* srow = xin + ((size_t)(b * H + yy) * W) * CIN;
#pragma unroll 1
    for (int cc = 0; cc < CIN; cc += 32) {
      // stage A: 3 taps x COUT rows x 64B (tap t = (dy+1)*3 + tt)
#pragma unroll
      for (int j = 0; j < APW; ++j) {
        int ch = wid * APW + j;
        int row = ch * 16 + l4;            // 0 .. 3*COUT-1 (tt-major)
        int tt = row / COUT, co = row % COUT;
        const ushort_t* src =
            wp + ((size_t)((dy + 1) * 3 + tt) * COUT + co) * CIN + cc + lb8;
        gload_lds16(src, &lA[ch * 512]);
      }
      // stage B: px = x0-1+row, valid rows < NT+2
      for (int ch = wid; ch < BCH; ch += 4) {
        int row = ch * 16 + l4;
        int xx = x0 - 1 + row;
        const ushort_t* src = (rowok && row < NT + 2 && xx >= 0 && xx < W)
                                  ? srow + (size_t)xx * CIN + cc + lb8
                                  : zer + lb8;
        gload_lds16(src, &lB[ch * 512]);
      }
      __syncthreads();
#pragma unroll
      for (int tt = 0; tt < 3; ++tt) {  // dx = tt-1; lB row = local_px + tt
        bf16x8 af[MFRAG], bfr[NFRAG];
#pragma unroll
        for (int m = 0; m < MFRAG; ++m)
          af[m] = *reinterpret_cast<const bf16x8*>(
              &lA[(tt * COUT + wr * MFRAG * 16 + m * 16 + lr) * 32 + kg * 8]);
#pragma unroll
        for (int n = 0; n < NFRAG; ++n)
          bfr[n] = *reinterpret_cast<const bf16x8*>(
              &lB[(wc * NFRAG * 16 + n * 16 + lr + tt) * 32 + kg * 8]);
#pragma unroll
        for (int m = 0; m < MFRAG; ++m)
#pragma unroll
          for (int n = 0; n < NFRAG; ++n)
            acc[m][n] = __builtin_amdgcn_mfma_f32_16x16x32_bf16(af[m], bfr[n], acc[m][n], 0, 0, 0);
      }
      __syncthreads();
    }
  }

  // epilogue: C/D layout col(=px)=lane&15, row(=co)=(lane>>4)*4+reg  [m89]
  const int lq = lane >> 4;
  ushort_t* orow = xout + ((size_t)(b * H + y) * W) * COUT;
#pragma unroll
  for (int m = 0; m < MFRAG; ++m) {
    const int co = wr * MFRAG * 16 + m * 16 + lq * 4;
    const float4 bv = *reinterpret_cast<const float4*>(&bias[co]);
#pragma unroll
    for (int n = 0; n < NFRAG; ++n) {
      const int px = x0 + wc * NFRAG * 16 + n * 16 + lr;
      f32x4 v = acc[m][n];
      ushort4 pk;
      pk.x = f2b(fmaxf(v[0] + bv.x, 0.f));
      pk.y = f2b(fmaxf(v[1] + bv.y, 0.f));
      pk.z = f2b(fmaxf(v[2] + bv.z, 0.f));
      pk.w = f2b(fmaxf(v[3] + bv.w, 0.f));
      *reinterpret_cast<ushort4*>(&orow[(size_t)px * COUT + co]) = pk;
    }
  }
}

// ---------------------------------------------------------------- det2 (1x1,128->1) + sigmoid + row-max fused
__global__ __launch_bounds__(384) void det2_rowmax(
    const ushort_t* __restrict__ dbuf, const float* __restrict__ w2,
    const float* __restrict__ b2, float* __restrict__ prob,
    float* __restrict__ tmp) {
  __shared__ float ws[128];
  __shared__ float pr[W];
  const int tid = threadIdx.x;
  if (tid < 128) ws[tid] = w2[tid];
  __syncthreads();
  const int p = blockIdx.x * W + tid;  // blockIdx.x = b*H + y
  const ushort_t* dp = dbuf + (size_t)p * 128;
  float acc = b2[0];
#pragma unroll
  for (int k = 0; k < 128; k += 8) {
    uint4 q = *reinterpret_cast<const uint4*>(dp + k);
    acc += __uint_as_float(q.x << 16) * ws[k + 0];
    acc += __uint_as_float(q.x & 0xffff0000u) * ws[k + 1];
    acc += __uint_as_float(q.y << 16) * ws[k + 2];
    acc += __uint_as_float(q.y & 0xffff0000u) * ws[k + 3];
    acc += __uint_as_float(q.z << 16) * ws[k + 4];
    acc += __uint_as_float(q.z & 0xffff0000u) * ws[k + 5];
    acc += __uint_as_float(q.w << 16) * ws[k + 6];
    acc += __uint_as_float(q.w & 0xffff0000u) * ws[k + 7];
  }
  float pv = 1.f / (1.f + expf(-acc));
  prob[p] = pv;
  pr[tid] = pv;
  __syncthreads();
  float m = -1e30f;
#pragma unroll
  for (int d = -NMSD; d <= NMSD; ++d) {
    int xx = tid + d;
    if (xx >= 0 && xx < W) m = fmaxf(m, pr[xx]);
  }
  tmp[p] = m;
}

// ---------------------------------------------------------------- col-max + candidate collection
__global__ __launch_bounds__(256) void colmax9_cand(
    const float* __restrict__ tmp, const float* __restrict__ prob,
    int* __restrict__ cnt, float* __restrict__ candv, int* __restrict__ candi) {
  const int p = blockIdx.x * 256 + threadIdx.x;
  const int b = p / HW, rem = p % HW;
  const int y = rem / W, x = rem % W;
  float m = -1e30f;
#pragma unroll
  for (int d = -NMSD; d <= NMSD; ++d) {
    int yy = y + d;
    if (yy >= 0 && yy < H) m = fmaxf(m, tmp[(size_t)b * HW + yy * W + x]);
  }
  float pv = prob[p];
  bool keep = (pv >= m) && (pv > THRESH) &&
              (y >= BORD) && (y < H - BORD) && (x >= BORD) && (x < W - BORD);
  if (keep) {
    int pos = atomicAdd(&cnt[b], 1);
    if (pos < CAP) {
      candv[b * CAP + pos] = pv;
      candi[b * CAP + pos] = rem;
    }
  }
}

// ---------------------------------------------------------------- top-k with JAX tie semantics
__global__ __launch_bounds__(256) void select_topk(
    const int* __restrict__ cnt, const float* __restrict__ candv,
    const int* __restrict__ candi, float* __restrict__ pos_out,
    int* __restrict__ topi_g) {
  __shared__ float sv[SORTN];
  __shared__ int si[SORTN];
  __shared__ int tail[TOPK];
  const int b = blockIdx.x, tid = threadIdx.x;
  int nc = cnt[b];
  if (nc > CAP) nc = CAP;
  for (int j = tid; j < SORTN; j += 256) {
    if (j < nc) {
      sv[j] = candv[b * CAP + j];
      si[j] = candi[b * CAP + j];
    } else {
      sv[j] = -1.f;
      si[j] = 0x7fffffff;
    }
  }
  __syncthreads();
  if (nc > 0) {  // block-uniform: skip sort when candidate set empty
    for (int k = 2; k <= SORTN; k <<= 1) {
      for (int j = k >> 1; j > 0; j >>= 1) {
        for (int i = tid; i < SORTN; i += 256) {
          int l = i ^ j;
          if (l > i) {
            float vi = sv[i], vl = sv[l];
            int ii = si[i], il = si[l];
            bool i_better = (vi > vl) || (vi == vl && ii < il);
            bool desc = ((i & k) == 0);
            bool sw = desc ? (!i_better) : i_better;
            if (sw) {
              sv[i] = vl; sv[l] = vi;
              si[i] = il; si[l] = ii;
            }
          }
        }
        __syncthreads();
      }
    }
  }
  if (tid == 0) {
    int need = TOPK - nc;
    if (need < 0) need = 0;
    int idx = 0, filled = 0;
    while (filled < need && idx < HW) {
      bool used = false;
      for (int q = 0; q < nc; ++q)
        if (si[q] == idx) { used = true; break; }
      if (!used) tail[filled++] = idx;
      ++idx;
    }
  }
  __syncthreads();
  for (int k2 = tid; k2 < TOPK; k2 += 256) {
    float v; int idx;
    if (k2 < nc) { v = sv[k2]; idx = si[k2]; }
    else         { v = 0.f;    idx = tail[k2 - nc]; }
    pos_out[((size_t)b * TOPK + k2) * 3 + 0] = (float)(idx / W);
    pos_out[((size_t)b * TOPK + k2) * 3 + 1] = (float)(idx % W);
    pos_out[((size_t)b * TOPK + k2) * 3 + 2] = v;
    topi_g[b * TOPK + k2] = idx;
  }
}

// ---------------------------------------------------------------- descriptor head at keypoints only
// xf gather is t-major (k' = t*128+ci): consecutive threads read consecutive
// ci at one tap -> coalesced 256B runs. w1t repacked in matching order.
__global__ __launch_bounds__(256) void des_head(
    const ushort_t* __restrict__ feats, const int* __restrict__ topi_g,
    const ushort_t* __restrict__ w1t, const float* __restrict__ b1,
    const float* __restrict__ w2t, const float* __restrict__ b2,
    const float* __restrict__ scale, float* __restrict__ desc_out) {
  __shared__ __align__(16) float xf[1152];  // k' = t*128 + ci
  __shared__ __align__(16) float es[256];
  __shared__ float rs[128];
  __shared__ float nrm_s;
  const int g = blockIdx.x;
  const int b = g / TOPK;
  const int tid = threadIdx.x;
  const int idx = topi_g[g];
  const int y = idx / W, x = idx % W;
  for (int j = tid; j < 1152; j += 256) {
    int t = j >> 7, ci = j & 127;
    int yy = y + t / 3 - 1, xx = x + t % 3 - 1;
    xf[j] = (yy >= 0 && yy < H && xx >= 0 && xx < W)
                ? b2f(feats[((size_t)(b * H + yy) * W + xx) * 128 + ci])
                : 0.f;
  }
  __syncthreads();
  float e = b1[tid];
  const ushort4* w4p = reinterpret_cast<const ushort4*>(w1t);
#pragma unroll 4
  for (int k4 = 0; k4 < 288; ++k4) {
    ushort4 wv = w4p[(size_t)k4 * 256 + tid];
    float4 x4 = *reinterpret_cast<const float4*>(&xf[k4 * 4]);
    e += b2f(wv.x) * x4.x + b2f(wv.y) * x4.y + b2f(wv.z) * x4.z + b2f(wv.w) * x4.w;
  }
  es[tid] = fmaxf(e, 0.f);
  __syncthreads();
  if (tid < 128) {
    float r = b2[tid];
#pragma unroll 4
    for (int o = 0; o < 256; ++o) r += es[o] * w2t[o * 128 + tid];
    rs[tid] = r;
  }
  __syncthreads();
  if (tid < 64) {
    float v = rs[tid] * rs[tid] + rs[tid + 64] * rs[tid + 64];
    for (int off = 32; off > 0; off >>= 1) v += __shfl_down(v, off);
    if (tid == 0) nrm_s = sqrtf(v);
  }
  __syncthreads();
  if (tid < 128) {
    float nrm = fmaxf(nrm_s, 1e-12f);
    desc_out[(size_t)g * 128 + tid] = rs[tid] * (scale[0] / nrm);
  }
}

// ---------------------------------------------------------------- launch
extern "C" void kernel_launch(void* const* d_in, const int* in_sizes, int n_in,
                              void* d_out, int out_size, void* d_ws, size_t ws_size,
                              hipStream_t stream) {
  (void)in_sizes; (void)n_in; (void)out_size; (void)ws_size;
  const float* images = (const float*)d_in[0];
  const float* bbw1 = (const float*)d_in[1];  const float* bbb1 = (const float*)d_in[2];
  const float* bbw2 = (const float*)d_in[3];  const float* bbb2 = (const float*)d_in[4];
  const float* bbw3 = (const float*)d_in[5];  const float* bbb3 = (const float*)d_in[6];
  const float* bbw4 = (const float*)d_in[7];  const float* bbb4 = (const float*)d_in[8];
  const float* dtw1 = (const float*)d_in[9];  const float* dtb1 = (const float*)d_in[10];
  const float* dtw2 = (const float*)d_in[11]; const float* dtb2 = (const float*)d_in[12];
  const float* dsw1 = (const float*)d_in[13]; const float* dsb1 = (const float*)d_in[14];
  const float* dsw2 = (const float*)d_in[15]; const float* dsb2 = (const float*)d_in[16];
  const float* scale = (const float*)d_in[17];

  char* ws = (char*)d_ws;
  constexpr size_t SZ64 = (size_t)BATCH * HW * 64 * 2;   // 37,748,736
  constexpr size_t SZ128 = (size_t)BATCH * HW * 128 * 2; // 75,497,472

  // Two big regions, time-multiplexed by dataflow (~155 MB total):
  //   region A [0, SZ128):        x1 + x2   -->  fts
  //   region B [SZ128, 2*SZ128):  x3        -->  dbuf
  ushort_t* x1   = (ushort_t*)ws;
  ushort_t* x2   = (ushort_t*)(ws + SZ64);
  ushort_t* x3   = (ushort_t*)(ws + SZ128);
  ushort_t* fts  = (ushort_t*)ws;              // alias x1+x2
  ushort_t* dbuf = (ushort_t*)(ws + SZ128);    // alias x3

  size_t off = 2 * SZ128;
  auto alloc = [&](size_t bytes) {
    char* p = ws + off;
    off = (off + bytes + 255) & ~(size_t)255;
    return p;
  };
  float* prob = (float*)alloc((size_t)BATCH * HW * 4);
  float* tmp  = (float*)alloc((size_t)BATCH * HW * 4);
  ushort_t* wp2 = (ushort_t*)alloc(9 * 64 * 64 * 2);
  ushort_t* wp3 = (ushort_t*)alloc(9 * 128 * 64 * 2);
  ushort_t* wp4 = (ushort_t*)alloc(9 * 128 * 128 * 2);
  ushort_t* wpd = (ushort_t*)alloc(9 * 128 * 128 * 2);
  ushort_t* w1t = (ushort_t*)alloc(288 * 256 * 4 * 2);
  float*    w2t = (float*)alloc(256 * 128 * 4);
  ushort_t* zer = (ushort_t*)alloc(2048);
  int* cnt      = (int*)alloc(256);
  float* candv  = (float*)alloc((size_t)BATCH * CAP * 4);
  int* candi    = (int*)alloc((size_t)BATCH * CAP * 4);
  int* topi_g   = (int*)alloc((size_t)BATCH * TOPK * 4);

  float* desc_out = (float*)d_out;
  float* pos_out  = (float*)d_out + (size_t)BATCH * TOPK * 128;

  setup_all<<<2868, 256, 0, stream>>>(bbw2, wp2, bbw3, wp3, bbw4, wp4, dtw1, wpd,
                                      dsw1, w1t, dsw2, w2t, zer, cnt);

  conv1_kernel<<<BATCH * HW / 256, 256, 0, stream>>>(images, bbw1, bbb1, x1);
  conv3x3_mfma<64, 64, 2, 4, 128>  <<<dim3(3 * H, BATCH), 256, 0, stream>>>(x1, wp2, bbb2, x2, zer);
  conv3x3_mfma<64, 128, 4, 6, 192> <<<dim3(2 * H, BATCH), 256, 0, stream>>>(x2, wp3, bbb3, x3, zer);
  conv3x3_mfma<128, 128, 4, 6, 192><<<dim3(2 * H, BATCH), 256, 0, stream>>>(x3, wp4, bbb4, fts, zer);
  conv3x3_mfma<128, 128, 4, 6, 192><<<dim3(2 * H, BATCH), 256, 0, stream>>>(fts, wpd, dtb1, dbuf, zer);

  det2_rowmax<<<BATCH * H, 384, 0, stream>>>(dbuf, dtw2, dtb2, prob, tmp);
  colmax9_cand<<<BATCH * HW / 256, 256, 0, stream>>>(tmp, prob, cnt, candv, candi);
  select_topk<<<BATCH, 256, 0, stream>>>(cnt, candv, candi, pos_out, topi_g);
  des_head<<<BATCH * TOPK, 256, 0, stream>>>(fts, topi_g, w1t, dsb1, w2t, dsb2, scale, desc_out);
}

// Round 13
// 495.774 us; speedup vs baseline: 1.5031x; 1.0178x over previous
//
#include <hip/hip_runtime.h>
#include <hip/hip_bf16.h>

#define DEVI __device__ __forceinline__

typedef __bf16 bf16x8 __attribute__((ext_vector_type(8)));
typedef float  f32x4  __attribute__((ext_vector_type(4)));
typedef unsigned short ushort_t;

static constexpr int H = 384, W = 384, BATCH = 2, HW = H * W;
static constexpr int NMSD = 4, BORD = 4, TOPK = 500;
static constexpr float THRESH = 0.8f;
static constexpr int CAP = 2048;    // candidate capacity per image
static constexpr int SORTN = 2048;  // bitonic sort size (>= CAP)

DEVI ushort_t f2b(float f) {
  __hip_bfloat16 h = __float2bfloat16(f);
  ushort_t s;
  __builtin_memcpy(&s, &h, 2);
  return s;
}
DEVI float b2f(ushort_t u) { return __uint_as_float(((unsigned)u) << 16); }

DEVI void gload_lds16(const void* g, void* l) {
  __builtin_amdgcn_global_load_lds((const __attribute__((address_space(1))) void*)g,
                                   (__attribute__((address_space(3))) void*)l,
                                   16, 0, 0);
}

// ---------------------------------------------------------------- unified setup
// conv weights: OIHW fp32 [O][I][3][3] -> bf16 [9][O][I]  (round-4 validated layout)
DEVI void repack9(const float* __restrict__ src, ushort_t* __restrict__ dst,
                  int d, int O, int I) {
  int t = d / (O * I);
  int r = d % (O * I);
  int o = r / I, i = r % I;
  dst[d] = f2b(src[(o * I + i) * 9 + t]);
}

__global__ __launch_bounds__(256) void setup_all(
    const float* __restrict__ w2s, ushort_t* __restrict__ wp2,
    const float* __restrict__ w3s, ushort_t* __restrict__ wp3,
    const float* __restrict__ w4s, ushort_t* __restrict__ wp4,
    const float* __restrict__ wds, ushort_t* __restrict__ wpd,
    const float* __restrict__ dw1, ushort_t* __restrict__ w1t,
    const float* __restrict__ dw2, float* __restrict__ w2t,
    ushort_t* __restrict__ zer, int* __restrict__ cnt) {
  int d = blockIdx.x * 256 + threadIdx.x;
  if (d < 1024) { zer[d] = 0; if (d < 2) cnt[d] = 0; return; }
  d -= 1024;
  if (d < 36864)  { repack9(w2s, wp2, d, 64, 64);   return; }
  d -= 36864;
  if (d < 73728)  { repack9(w3s, wp3, d, 128, 64);  return; }
  d -= 73728;
  if (d < 147456) { repack9(w4s, wp4, d, 128, 128); return; }
  d -= 147456;
  if (d < 147456) { repack9(wds, wpd, d, 128, 128); return; }
  d -= 147456;
  if (d < 294912) {  // des_w1 [256][1152] -> bf16 [288][256][4], k reordered t-major
    int o = d / 1152, k = d % 1152;      // k = ci*9 + t (OIHW flat)
    int kp = (k % 9) * 128 + (k / 9);    // k' = t*128 + ci  (coalesced gather order)
    w1t[(size_t)(kp >> 2) * 1024 + o * 4 + (kp & 3)] = f2b(dw1[d]);
    return;
  }
  d -= 294912;
  if (d < 32768) {   // des_w2 [128][256] -> fp32 [256][128]
    int o = d / 128, c = d % 128;
    w2t[d] = dw2[c * 256 + o];
  }
}
// total elements = 1024+36864+73728+147456+147456+294912+32768 = 734208 = 2868*256

// ---------------------------------------------------------------- conv1 (1->64) fp32 direct, bf16 NHWC out
__global__ __launch_bounds__(256) void conv1_kernel(
    const float* __restrict__ img, const float* __restrict__ w,
    const float* __restrict__ bias, ushort_t* __restrict__ xout) {
  __shared__ __align__(16) float wt[9 * 64];
  __shared__ float bs[64];
  const int tid = threadIdx.x;
  for (int j = tid; j < 576; j += 256) {
    int co = j / 9, t = j % 9;
    wt[t * 64 + co] = w[j];
  }
  if (tid < 64) bs[tid] = bias[tid];
  __syncthreads();

  const int p = blockIdx.x * 256 + tid;
  const int b = p / HW, rem = p % HW;
  const int y = rem / W, x = rem % W;

  float in[9];
#pragma unroll
  for (int t = 0; t < 9; ++t) {
    int yy = y + t / 3 - 1, xx = x + t % 3 - 1;
    in[t] = (yy >= 0 && yy < H && xx >= 0 && xx < W) ? img[(size_t)b * HW + yy * W + xx] : 0.f;
  }
  float acc[64];
#pragma unroll
  for (int c = 0; c < 64; ++c) acc[c] = bs[c];
#pragma unroll
  for (int t = 0; t < 9; ++t) {
    float v = in[t];
#pragma unroll
    for (int c4 = 0; c4 < 16; ++c4) {
      float4 w4 = *reinterpret_cast<const float4*>(&wt[t * 64 + c4 * 4]);
      acc[c4 * 4 + 0] += w4.x * v;
      acc[c4 * 4 + 1] += w4.y * v;
      acc[c4 * 4 + 2] += w4.z * v;
      acc[c4 * 4 + 3] += w4.w * v;
    }
  }
  ushort_t* op = xout + (size_t)p * 64;
#pragma unroll
  for (int g = 0; g < 8; ++g) {
    uint4 u;
    u.x = (unsigned)f2b(fmaxf(acc[g * 8 + 0], 0.f)) | ((unsigned)f2b(fmaxf(acc[g * 8 + 1], 0.f)) << 16);
    u.y = (unsigned)f2b(fmaxf(acc[g * 8 + 2], 0.f)) | ((unsigned)f2b(fmaxf(acc[g * 8 + 3], 0.f)) << 16);
    u.z = (unsigned)f2b(fmaxf(acc[g * 8 + 4], 0.f)) | ((unsigned)f2b(fmaxf(acc[g * 8 + 5], 0.f)) << 16);
    u.w = (unsigned)f2b(fmaxf(acc[g * 8 + 6], 0.f)) | ((unsigned)f2b(fmaxf(acc[g * 8 + 7], 0.f)) << 16);
    *reinterpret_cast<uint4*>(op + g * 8) = u;
  }
}

// ---------------------------------------------------------------- 3x3 conv, bf16 MFMA implicit GEMM (v5)
// v4b structure + k-slot XOR swizzle (T2 / G4). Unswizzled, a fragment read
// has 16 lanes at 64B row-stride and a FIXED 16B k-slot -> banks {b,b+16}
// only = 8-way conflict (8.85e6/dispatch measured). Swizzle slot' =
// kg ^ ((row>>1)&3): 16 lanes -> 8 banks x 2-way (free, m136).
// Both-sides rule (#21): gload_lds LDS dest stays LINEAR; the per-lane
// GLOBAL source fetches slot (lane&3)^((lane>>3)&3) of its row; reads apply
// the same XOR keyed on absolute row.
template <int CIN, int COUT, int MFRAG, int NFRAG, int NT>
__global__ __launch_bounds__(256) void conv3x3_mfma(
    const ushort_t* __restrict__ xin, const ushort_t* __restrict__ wp,
    const float* __restrict__ bias, ushort_t* __restrict__ xout,
    const ushort_t* __restrict__ zer) {
  constexpr int ACH3 = 3 * COUT / 16;   // A chunks per phase (3 taps)
  constexpr int APW = ACH3 / 4;         // A chunks per wave
  constexpr int BCH = (NT + 2 + 15) / 16;  // staged B chunks (NT+2 halo rows)

  __shared__ __align__(16) ushort_t lA[3 * COUT * 32];  // [tt][co][32ci] swizzled slots
  __shared__ __align__(16) ushort_t lB[BCH * 16 * 32];  // [px-(x0-1)][32ci] swizzled slots

  const int x0 = (blockIdx.x % (W / NT)) * NT;
  const int y = blockIdx.x / (W / NT);
  const int b = blockIdx.y;

  const int tid = threadIdx.x;
  const int wid = tid >> 6, lane = tid & 63;
  const int wr = wid >> 1, wc = wid & 1;
  const int l4 = lane >> 2;        // staging row within 16-row chunk
  // swizzled k-slot this lane must FETCH so that linear-dest write + swizzled
  // read compose to identity: slot = (lane&3) ^ ((row>>1)&3), row%16 = l4
  const int lb8 = (((lane & 3) ^ ((lane >> 3) & 3))) * 8;
  const int kg = lane >> 4;        // k-group 0..3
  const int lr = lane & 15;

  const f32x4 fz = {0.f, 0.f, 0.f, 0.f};
  f32x4 acc[MFRAG][NFRAG];
#pragma unroll
  for (int m = 0; m < MFRAG; ++m)
#pragma unroll
    for (int n = 0; n < NFRAG; ++n) acc[m][n] = fz;

#pragma unroll 1
  for (int dy = -1; dy <= 1; ++dy) {
    const int yy = y + dy;
    const bool rowok = (yy >= 0) && (yy < H);
    const ushort_t* srow = xin + ((size_t)(b * H + yy) * W) * CIN;
#pragma unroll 1
    for (int cc = 0; cc < CIN; cc += 32) {
      // stage A: 3 taps x COUT rows x 64B (tap t = (dy+1)*3 + tt)
#pragma unroll
      for (int j = 0; j < APW; ++j) {
        int ch = wid * APW + j;
        int row = ch * 16 + l4;            // 0 .. 3*COUT-1 (tt-major)
        int tt = row / COUT, co = row % COUT;
        const ushort_t* src =
            wp + ((size_t)((dy + 1) * 3 + tt) * COUT + co) * CIN + cc + lb8;
        gload_lds16(src, &lA[ch * 512]);
      }
      // stage B: px = x0-1+row, valid rows < NT+2
      for (int ch = wid; ch < BCH; ch += 4) {
        int row = ch * 16 + l4;
        int xx = x0 - 1 + row;
        const ushort_t* src = (rowok && row < NT + 2 && xx >= 0 && xx < W)
                                  ? srow + (size_t)xx * CIN + lb8
                                  : zer + lb8;
        gload_lds16(src, &lB[ch * 512]);
      }
      __syncthreads();
#pragma unroll
      for (int tt = 0; tt < 3; ++tt) {  // dx = tt-1; lB row = local_px + tt
        bf16x8 af[MFRAG], bfr[NFRAG];
#pragma unroll
        for (int m = 0; m < MFRAG; ++m) {
          const int ra = tt * COUT + wr * MFRAG * 16 + m * 16 + lr;
          const int sa = kg ^ ((ra >> 1) & 3);
          af[m] = *reinterpret_cast<const bf16x8*>(&lA[ra * 32 + sa * 8]);
        }
#pragma unroll
        for (int n = 0; n < NFRAG; ++n) {
          const int rb = wc * NFRAG * 16 + n * 16 + lr + tt;
          const int sb = kg ^ ((rb >> 1) & 3);
          bfr[n] = *reinterpret_cast<const bf16x8*>(&lB[rb * 32 + sb * 8]);
        }
#pragma unroll
        for (int m = 0; m < MFRAG; ++m)
#pragma unroll
          for (int n = 0; n < NFRAG; ++n)
            acc[m][n] = __builtin_amdgcn_mfma_f32_16x16x32_bf16(af[m], bfr[n], acc[m][n], 0, 0, 0);
      }
      __syncthreads();
    }
  }

  // epilogue: C/D layout col(=px)=lane&15, row(=co)=(lane>>4)*4+reg  [m89]
  const int lq = lane >> 4;
  ushort_t* orow = xout + ((size_t)(b * H + y) * W) * COUT;
#pragma unroll
  for (int m = 0; m < MFRAG; ++m) {
    const int co = wr * MFRAG * 16 + m * 16 + lq * 4;
    const float4 bv = *reinterpret_cast<const float4*>(&bias[co]);
#pragma unroll
    for (int n = 0; n < NFRAG; ++n) {
      const int px = x0 + wc * NFRAG * 16 + n * 16 + lr;
      f32x4 v = acc[m][n];
      ushort4 pk;
      pk.x = f2b(fmaxf(v[0] + bv.x, 0.f));
      pk.y = f2b(fmaxf(v[1] + bv.y, 0.f));
      pk.z = f2b(fmaxf(v[2] + bv.z, 0.f));
      pk.w = f2b(fmaxf(v[3] + bv.w, 0.f));
      *reinterpret_cast<ushort4*>(&orow[(size_t)px * COUT + co]) = pk;
    }
  }
}

// ---------------------------------------------------------------- det2 (1x1,128->1) + sigmoid + row-max fused
__global__ __launch_bounds__(384) void det2_rowmax(
    const ushort_t* __restrict__ dbuf, const float* __restrict__ w2,
    const float* __restrict__ b2, float* __restrict__ prob,
    float* __restrict__ tmp) {
  __shared__ float ws[128];
  __shared__ float pr[W];
  const int tid = threadIdx.x;
  if (tid < 128) ws[tid] = w2[tid];
  __syncthreads();
  const int p = blockIdx.x * W + tid;  // blockIdx.x = b*H + y
  const ushort_t* dp = dbuf + (size_t)p * 128;
  float acc = b2[0];
#pragma unroll
  for (int k = 0; k < 128; k += 8) {
    uint4 q = *reinterpret_cast<const uint4*>(dp + k);
    acc += __uint_as_float(q.x << 16) * ws[k + 0];
    acc += __uint_as_float(q.x & 0xffff0000u) * ws[k + 1];
    acc += __uint_as_float(q.y << 16) * ws[k + 2];
    acc += __uint_as_float(q.y & 0xffff0000u) * ws[k + 3];
    acc += __uint_as_float(q.z << 16) * ws[k + 4];
    acc += __uint_as_float(q.z & 0xffff0000u) * ws[k + 5];
    acc += __uint_as_float(q.w << 16) * ws[k + 6];
    acc += __uint_as_float(q.w & 0xffff0000u) * ws[k + 7];
  }
  float pv = 1.f / (1.f + expf(-acc));
  prob[p] = pv;
  pr[tid] = pv;
  __syncthreads();
  float m = -1e30f;
#pragma unroll
  for (int d = -NMSD; d <= NMSD; ++d) {
    int xx = tid + d;
    if (xx >= 0 && xx < W) m = fmaxf(m, pr[xx]);
  }
  tmp[p] = m;
}

// ---------------------------------------------------------------- col-max + candidate collection
__global__ __launch_bounds__(256) void colmax9_cand(
    const float* __restrict__ tmp, const float* __restrict__ prob,
    int* __restrict__ cnt, float* __restrict__ candv, int* __restrict__ candi) {
  const int p = blockIdx.x * 256 + threadIdx.x;
  const int b = p / HW, rem = p % HW;
  const int y = rem / W, x = rem % W;
  float m = -1e30f;
#pragma unroll
  for (int d = -NMSD; d <= NMSD; ++d) {
    int yy = y + d;
    if (yy >= 0 && yy < H) m = fmaxf(m, tmp[(size_t)b * HW + yy * W + x]);
  }
  float pv = prob[p];
  bool keep = (pv >= m) && (pv > THRESH) &&
              (y >= BORD) && (y < H - BORD) && (x >= BORD) && (x < W - BORD);
  if (keep) {
    int pos = atomicAdd(&cnt[b], 1);
    if (pos < CAP) {
      candv[b * CAP + pos] = pv;
      candi[b * CAP + pos] = rem;
    }
  }
}

// ---------------------------------------------------------------- top-k with JAX tie semantics
__global__ __launch_bounds__(256) void select_topk(
    const int* __restrict__ cnt, const float* __restrict__ candv,
    const int* __restrict__ candi, float* __restrict__ pos_out,
    int* __restrict__ topi_g) {
  __shared__ float sv[SORTN];
  __shared__ int si[SORTN];
  __shared__ int tail[TOPK];
  const int b = blockIdx.x, tid = threadIdx.x;
  int nc = cnt[b];
  if (nc > CAP) nc = CAP;
  for (int j = tid; j < SORTN; j += 256) {
    if (j < nc) {
      sv[j] = candv[b * CAP + j];
      si[j] = candi[b * CAP + j];
    } else {
      sv[j] = -1.f;
      si[j] = 0x7fffffff;
    }
  }
  __syncthreads();
  if (nc > 0) {  // block-uniform: skip sort when candidate set empty
    for (int k = 2; k <= SORTN; k <<= 1) {
      for (int j = k >> 1; j > 0; j >>= 1) {
        for (int i = tid; i < SORTN; i += 256) {
          int l = i ^ j;
          if (l > i) {
            float vi = sv[i], vl = sv[l];
            int ii = si[i], il = si[l];
            bool i_better = (vi > vl) || (vi == vl && ii < il);
            bool desc = ((i & k) == 0);
            bool sw = desc ? (!i_better) : i_better;
            if (sw) {
              sv[i] = vl; sv[l] = vi;
              si[i] = il; si[l] = ii;
            }
          }
        }
        __syncthreads();
      }
    }
  }
  if (tid == 0) {
    int need = TOPK - nc;
    if (need < 0) need = 0;
    int idx = 0, filled = 0;
    while (filled < need && idx < HW) {
      bool used = false;
      for (int q = 0; q < nc; ++q)
        if (si[q] == idx) { used = true; break; }
      if (!used) tail[filled++] = idx;
      ++idx;
    }
  }
  __syncthreads();
  for (int k2 = tid; k2 < TOPK; k2 += 256) {
    float v; int idx;
    if (k2 < nc) { v = sv[k2]; idx = si[k2]; }
    else         { v = 0.f;    idx = tail[k2 - nc]; }
    pos_out[((size_t)b * TOPK + k2) * 3 + 0] = (float)(idx / W);
    pos_out[((size_t)b * TOPK + k2) * 3 + 1] = (float)(idx % W);
    pos_out[((size_t)b * TOPK + k2) * 3 + 2] = v;
    topi_g[b * TOPK + k2] = idx;
  }
}

// ---------------------------------------------------------------- descriptor head at keypoints only
// xf gather is t-major (k' = t*128+ci): consecutive threads read consecutive
// ci at one tap -> coalesced 256B runs. w1t repacked in matching order.
__global__ __launch_bounds__(256) void des_head(
    const ushort_t* __restrict__ feats, const int* __restrict__ topi_g,
    const ushort_t* __restrict__ w1t, const float* __restrict__ b1,
    const float* __restrict__ w2t, const float* __restrict__ b2,
    const float* __restrict__ scale, float* __restrict__ desc_out) {
  __shared__ __align__(16) float xf[1152];  // k' = t*128 + ci
  __shared__ __align__(16) float es[256];
  __shared__ float rs[128];
  __shared__ float nrm_s;
  const int g = blockIdx.x;
  const int b = g / TOPK;
  const int tid = threadIdx.x;
  const int idx = topi_g[g];
  const int y = idx / W, x = idx % W;
  for (int j = tid; j < 1152; j += 256) {
    int t = j >> 7, ci = j & 127;
    int yy = y + t / 3 - 1, xx = x + t % 3 - 1;
    xf[j] = (yy >= 0 && yy < H && xx >= 0 && xx < W)
                ? b2f(feats[((size_t)(b * H + yy) * W + xx) * 128 + ci])
                : 0.f;
  }
  __syncthreads();
  float e = b1[tid];
  const ushort4* w4p = reinterpret_cast<const ushort4*>(w1t);
#pragma unroll 4
  for (int k4 = 0; k4 < 288; ++k4) {
    ushort4 wv = w4p[(size_t)k4 * 256 + tid];
    float4 x4 = *reinterpret_cast<const float4*>(&xf[k4 * 4]);
    e += b2f(wv.x) * x4.x + b2f(wv.y) * x4.y + b2f(wv.z) * x4.z + b2f(wv.w) * x4.w;
  }
  es[tid] = fmaxf(e, 0.f);
  __syncthreads();
  if (tid < 128) {
    float r = b2[tid];
#pragma unroll 4
    for (int o = 0; o < 256; ++o) r += es[o] * w2t[o * 128 + tid];
    rs[tid] = r;
  }
  __syncthreads();
  if (tid < 64) {
    float v = rs[tid] * rs[tid] + rs[tid + 64] * rs[tid + 64];
    for (int off = 32; off > 0; off >>= 1) v += __shfl_down(v, off);
    if (tid == 0) nrm_s = sqrtf(v);
  }
  __syncthreads();
  if (tid < 128) {
    float nrm = fmaxf(nrm_s, 1e-12f);
    desc_out[(size_t)g * 128 + tid] = rs[tid] * (scale[0] / nrm);
  }
}

// ---------------------------------------------------------------- launch
extern "C" void kernel_launch(void* const* d_in, const int* in_sizes, int n_in,
                              void* d_out, int out_size, void* d_ws, size_t ws_size,
                              hipStream_t stream) {
  (void)in_sizes; (void)n_in; (void)out_size; (void)ws_size;
  const float* images = (const float*)d_in[0];
  const float* bbw1 = (const float*)d_in[1];  const float* bbb1 = (const float*)d_in[2];
  const float* bbw2 = (const float*)d_in[3];  const float* bbb2 = (const float*)d_in[4];
  const float* bbw3 = (const float*)d_in[5];  const float* bbb3 = (const float*)d_in[6];
  const float* bbw4 = (const float*)d_in[7];  const float* bbb4 = (const float*)d_in[8];
  const float* dtw1 = (const float*)d_in[9];  const float* dtb1 = (const float*)d_in[10];
  const float* dtw2 = (const float*)d_in[11]; const float* dtb2 = (const float*)d_in[12];
  const float* dsw1 = (const float*)d_in[13]; const float* dsb1 = (const float*)d_in[14];
  const float* dsw2 = (const float*)d_in[15]; const float* dsb2 = (const float*)d_in[16];
  const float* scale = (const float*)d_in[17];

  char* ws = (char*)d_ws;
  constexpr size_t SZ64 = (size_t)BATCH * HW * 64 * 2;   // 37,748,736
  constexpr size_t SZ128 = (size_t)BATCH * HW * 128 * 2; // 75,497,472

  // Two big regions, time-multiplexed by dataflow (~155 MB total):
  //   region A [0, SZ128):        x1 + x2   -->  fts
  //   region B [SZ128, 2*SZ128):  x3        -->  dbuf
  ushort_t* x1   = (ushort_t*)ws;
  ushort_t* x2   = (ushort_t*)(ws + SZ64);
  ushort_t* x3   = (ushort_t*)(ws + SZ128);
  ushort_t* fts  = (ushort_t*)ws;              // alias x1+x2
  ushort_t* dbuf = (ushort_t*)(ws + SZ128);    // alias x3

  size_t off = 2 * SZ128;
  auto alloc = [&](size_t bytes) {
    char* p = ws + off;
    off = (off + bytes + 255) & ~(size_t)255;
    return p;
  };
  float* prob = (float*)alloc((size_t)BATCH * HW * 4);
  float* tmp  = (float*)alloc((size_t)BATCH * HW * 4);
  ushort_t* wp2 = (ushort_t*)alloc(9 * 64 * 64 * 2);
  ushort_t* wp3 = (ushort_t*)alloc(9 * 128 * 64 * 2);
  ushort_t* wp4 = (ushort_t*)alloc(9 * 128 * 128 * 2);
  ushort_t* wpd = (ushort_t*)alloc(9 * 128 * 128 * 2);
  ushort_t* w1t = (ushort_t*)alloc(288 * 256 * 4 * 2);
  float*    w2t = (float*)alloc(256 * 128 * 4);
  ushort_t* zer = (ushort_t*)alloc(2048);
  int* cnt      = (int*)alloc(256);
  float* candv  = (float*)alloc((size_t)BATCH * CAP * 4);
  int* candi    = (int*)alloc((size_t)BATCH * CAP * 4);
  int* topi_g   = (int*)alloc((size_t)BATCH * TOPK * 4);

  float* desc_out = (float*)d_out;
  float* pos_out  = (float*)d_out + (size_t)BATCH * TOPK * 128;

  setup_all<<<2868, 256, 0, stream>>>(bbw2, wp2, bbw3, wp3, bbw4, wp4, dtw1, wpd,
                                      dsw1, w1t, dsw2, w2t, zer, cnt);

  conv1_kernel<<<BATCH * HW / 256, 256, 0, stream>>>(images, bbw1, bbb1, x1);
  conv3x3_mfma<64, 64, 2, 4, 128>  <<<dim3(3 * H, BATCH), 256, 0, stream>>>(x1, wp2, bbb2, x2, zer);
  conv3x3_mfma<64, 128, 4, 6, 192> <<<dim3(2 * H, BATCH), 256, 0, stream>>>(x2, wp3, bbb3, x3, zer);
  conv3x3_mfma<128, 128, 4, 6, 192><<<dim3(2 * H, BATCH), 256, 0, stream>>>(x3, wp4, bbb4, fts, zer);
  conv3x3_mfma<128, 128, 4, 6, 192><<<dim3(2 * H, BATCH), 256, 0, stream>>>(fts, wpd, dtb1, dbuf, zer);

  det2_rowmax<<<BATCH * H, 384, 0, stream>>>(dbuf, dtw2, dtb2, prob, tmp);
  colmax9_cand<<<BATCH * HW / 256, 256, 0, stream>>>(tmp, prob, cnt, candv, candi);
  select_topk<<<BATCH, 256, 0, stream>>>(cnt, candv, candi, pos_out, topi_g);
  des_head<<<BATCH * TOPK, 256, 0, stream>>>(fts, topi_g, w1t, dsb1, w2t, dsb2, scale, desc_out);
}